// Round 7
// baseline (564.881 us; speedup 1.0000x reference)
//
#include <hip/hip_runtime.h>

#define KD 64        // embedding dim
#define NPB 64       // nodes per bucket (bucket = dst >> 6)
#define SCAN_BLK 256

// ---------------- bucket build ----------------

// LDS-aggregated histogram of dst>>6 (NB counters, dynamic LDS)
__global__ void bhist_kernel(const int* __restrict__ dst, int* __restrict__ cntb,
                             int E, int NB) {
    extern __shared__ int lcnt[];
    for (int i = threadIdx.x; i < NB; i += blockDim.x) lcnt[i] = 0;
    __syncthreads();
    for (int i = blockIdx.x * blockDim.x + threadIdx.x; i < E; i += gridDim.x * blockDim.x)
        atomicAdd(&lcnt[dst[i] >> 6], 1);
    __syncthreads();
    for (int i = threadIdx.x; i < NB; i += blockDim.x) {
        int v = lcnt[i];
        if (v) atomicAdd(&cntb[i], v);
    }
}

// block-level exclusive scan; blk_sums gets per-block totals
__global__ void scan1_kernel(const int* __restrict__ cnt, int* __restrict__ optr,
                             int* __restrict__ blk_sums, int n) {
    __shared__ int s[SCAN_BLK];
    int t = threadIdx.x;
    int g = blockIdx.x * SCAN_BLK + t;
    int v = (g < n) ? cnt[g] : 0;
    s[t] = v;
    __syncthreads();
    for (int off = 1; off < SCAN_BLK; off <<= 1) {
        int add = (t >= off) ? s[t - off] : 0;
        __syncthreads();
        s[t] += add;
        __syncthreads();
    }
    if (g < n) optr[g] = s[t] - v;               // exclusive
    if (t == SCAN_BLK - 1) blk_sums[blockIdx.x] = s[t];
}

__global__ void scan2_kernel(int* __restrict__ blk_sums, int nblk) {
    __shared__ int s[1024];
    int t = threadIdx.x;
    int v = (t < nblk) ? blk_sums[t] : 0;
    s[t] = v;
    __syncthreads();
    for (int off = 1; off < 1024; off <<= 1) {
        int add = (t >= off) ? s[t - off] : 0;
        __syncthreads();
        s[t] += add;
        __syncthreads();
    }
    if (t < nblk) blk_sums[t] = s[t] - v;        // exclusive
}

// finalize bucket ptr, init cursor
__global__ void scan3b_kernel(int* __restrict__ bptr, const int* __restrict__ blk_sums,
                              int* __restrict__ cursor, int NB, int E) {
    int g = blockIdx.x * 256 + threadIdx.x;
    if (g < NB) {
        int v = bptr[g] + blk_sums[g >> 8];
        bptr[g] = v;
        cursor[g] = v;
    }
    if (g == 0) bptr[NB] = E;
}

// XCD-partitioned partition: blocks with blockIdx&7==g handle buckets with
// bucket&7==g (default round-robin dispatch puts them on one XCD, so each
// frontier cache line is owned by a single L2 -> writes merge to full lines).
// Each of the 8 groups grid-strides the FULL edge list.
__global__ void part_kernel(const int* __restrict__ src, const int* __restrict__ dst,
                            int* __restrict__ cursor, unsigned int* __restrict__ staged,
                            int E) {
    int g    = blockIdx.x & 7;                   // bucket group == intended XCD
    int bsub = blockIdx.x >> 3;                  // block index within group
    int nsub = gridDim.x >> 3;                   // blocks per group
    for (int e = bsub * (int)blockDim.x + (int)threadIdx.x; e < E;
         e += nsub * (int)blockDim.x) {
        int d = dst[e];
        if (((d >> 6) & 7) == g) {
            int p = atomicAdd(&cursor[d >> 6], 1);
            staged[p] = (unsigned int)src[e] | (((unsigned int)d & 63u) << 18);
        }
    }
}

// per-bucket exact counting sort (writes stay inside the bucket's contiguous
// window of sorted_src -> L2-merged). Also emits row_ptr and r for its 64 nodes.
__global__ __launch_bounds__(256)
void bsort_kernel(const unsigned int* __restrict__ staged, const int* __restrict__ bptr,
                  int* __restrict__ sorted_src, int* __restrict__ row_ptr,
                  float* __restrict__ r, int n_nodes, int NB, int E) {
    __shared__ int lcnt[NPB];
    __shared__ int lofs[NPB];
    int b = blockIdx.x;
    int tid = threadIdx.x;
    if (tid < NPB) lcnt[tid] = 0;
    __syncthreads();
    int begin = bptr[b], end = bptr[b + 1];
    // pass 1: per-node counts
    for (int i = begin + tid; i < end; i += 256)
        atomicAdd(&lcnt[(staged[i] >> 18) & 63u], 1);
    __syncthreads();
    // exclusive scan of 64 counters (wave 0, lanes 0..63 via shfl_up)
    if (tid < 64) {
        int v = lcnt[tid];
        int s = v;
        for (int off = 1; off < 64; off <<= 1) {
            int u = __shfl_up(s, off);
            if ((tid & 63) >= off) s += u;
        }
        lofs[tid] = s - v;                       // exclusive
        int node = b * NPB + tid;
        if (node < n_nodes) {
            row_ptr[node] = begin + (s - v);
            r[node] = rsqrtf(fmaxf((float)v, 1.0f));
        }
        lcnt[tid] = 0;                           // reuse as cursor
    }
    if (b == 0 && tid == 0) row_ptr[n_nodes] = E;
    __syncthreads();
    // pass 2: scatter within bucket window
    for (int i = begin + tid; i < end; i += 256) {
        unsigned int u = staged[i];
        int ld = (u >> 18) & 63u;
        int p = begin + lofs[ld] + atomicAdd(&lcnt[ld], 1);
        sorted_src[p] = (int)(u & 0x3FFFFu);
    }
}

// ---------------- embedding kernels ----------------

// x0 = (Gu+Gut | Gi+Git); out = x0; xs = x0 * r[node]  (all f32)
__global__ void combine_kernel(const float4* __restrict__ Gu, const float4* __restrict__ Gi,
                               const float4* __restrict__ Gut, const float4* __restrict__ Git,
                               const float* __restrict__ r,
                               float4* __restrict__ out, float4* __restrict__ xs,
                               int nu4, int total4) {
    for (int i = blockIdx.x * blockDim.x + threadIdx.x; i < total4; i += gridDim.x * blockDim.x) {
        float4 a, b;
        if (i < nu4) { a = Gu[i]; b = Gut[i]; }
        else         { a = Gi[i - nu4]; b = Git[i - nu4]; }
        float4 c;
        c.x = a.x + b.x; c.y = a.y + b.y; c.z = a.z + b.z; c.w = a.w + b.w;
        out[i] = c;
        float rr = r[i >> 4];   // 16 float4 per node row
        float4 sc;
        sc.x = c.x * rr; sc.y = c.y * rr; sc.z = c.z * rr; sc.w = c.w * rr;
        xs[i] = sc;
    }
}

// one wave per dst node; 4 subgroups x 16 lanes; each subgroup processes 4 edges
// per iteration with 4 INDEPENDENT float4 loads issued before accumulation.
// y = acc * r; out += alpha*y; xs_next = y * r (skip on last layer).
__global__ __launch_bounds__(256)
void gather_kernel(const int* __restrict__ row_ptr, const int* __restrict__ sorted_src,
                   const float* __restrict__ r, const float4* __restrict__ xs,
                   float4* __restrict__ out, float4* __restrict__ xs_next,
                   float alpha, int N, int last) {
    int wid = (blockIdx.x * blockDim.x + threadIdx.x) >> 6;
    int lane = threadIdx.x & 63;
    if (wid >= N) return;
    int start = row_ptr[wid];
    int end   = row_ptr[wid + 1];
    int sub = lane >> 4;      // edge subgroup 0..3
    int li  = lane & 15;      // float4 slot within the 64-dim row

    float ax = 0.f, ay = 0.f, az = 0.f, aw = 0.f;
    for (int base = start; base < end; base += 64) {
        int nb = end - base; if (nb > 64) nb = 64;
        int eaddr = base + lane;
        int laste = end - 1;
        if (eaddr > laste) eaddr = laste;
        int es = sorted_src[eaddr];              // 64 edge ids (clamped tail)
        for (int c = 0; c < nb; c += 16) {
            int j0 = c + sub * 4;
            int s0 = __shfl(es, j0 + 0);
            int s1 = __shfl(es, j0 + 1);
            int s2 = __shfl(es, j0 + 2);
            int s3 = __shfl(es, j0 + 3);
            if (j0 < nb) {
                float m0 = 1.f;
                float m1 = (j0 + 1 < nb) ? 1.f : 0.f;
                float m2 = (j0 + 2 < nb) ? 1.f : 0.f;
                float m3 = (j0 + 3 < nb) ? 1.f : 0.f;
                float4 v0 = xs[s0 * 16 + li];
                float4 v1 = xs[s1 * 16 + li];
                float4 v2 = xs[s2 * 16 + li];
                float4 v3 = xs[s3 * 16 + li];
                ax += m0 * v0.x + m1 * v1.x + m2 * v2.x + m3 * v3.x;
                ay += m0 * v0.y + m1 * v1.y + m2 * v2.y + m3 * v3.y;
                az += m0 * v0.z + m1 * v1.z + m2 * v2.z + m3 * v3.z;
                aw += m0 * v0.w + m1 * v1.w + m2 * v2.w + m3 * v3.w;
            }
        }
    }
    ax += __shfl_xor(ax, 16); ay += __shfl_xor(ay, 16);
    az += __shfl_xor(az, 16); aw += __shfl_xor(aw, 16);
    ax += __shfl_xor(ax, 32); ay += __shfl_xor(ay, 32);
    az += __shfl_xor(az, 32); aw += __shfl_xor(aw, 32);

    if (lane < 16) {
        float rr = r[wid];
        float yx = ax * rr, yy = ay * rr, yz = az * rr, yw = aw * rr;
        int idx = wid * 16 + lane;
        float4 o = out[idx];
        o.x += alpha * yx; o.y += alpha * yy; o.z += alpha * yz; o.w += alpha * yw;
        out[idx] = o;
        if (!last) {
            float4 p;
            p.x = yx * rr; p.y = yy * rr; p.z = yz * rr; p.w = yw * rr;
            xs_next[idx] = p;
        }
    }
}

// ---------------- launch ----------------

extern "C" void kernel_launch(void* const* d_in, const int* in_sizes, int n_in,
                              void* d_out, int out_size, void* d_ws, size_t ws_size,
                              hipStream_t stream) {
    const float* Gu  = (const float*)d_in[0];
    const float* Gi  = (const float*)d_in[1];
    const float* Gut = (const float*)d_in[2];
    const float* Git = (const float*)d_in[3];
    const int*   edge_index = (const int*)d_in[4];
    const int n_layers = 3;

    const int nuK = in_sizes[0];
    const int niK = in_sizes[1];
    const int n_nodes = (nuK + niK) / KD;       // 150000
    const int E = in_sizes[4] / 2;              // 2,000,000
    const int totalK = nuK + niK;
    const int total4 = totalK / 4;
    const int nu4 = nuK / 4;
    const int NB = (n_nodes + NPB - 1) / NPB;   // 2344 buckets

    const int* src = edge_index;
    const int* dst = edge_index + E;

    auto align_up = [](size_t v) { return (v + 255) & ~(size_t)255; };
    char* ws = (char*)d_ws;
    size_t off = 0;
    int*          cntb       = (int*)(ws + off);          off += align_up((size_t)NB * 4);
    int*          bptr       = (int*)(ws + off);          off += align_up((size_t)(NB + 1) * 4);
    int*          blk_sums   = (int*)(ws + off);          off += align_up((size_t)1024 * 4);
    int*          cursor     = (int*)(ws + off);          off += align_up((size_t)NB * 4);
    int*          row_ptr    = (int*)(ws + off);          off += align_up((size_t)(n_nodes + 1) * 4);
    float*        r          = (float*)(ws + off);        off += align_up((size_t)n_nodes * 4);
    unsigned int* staged     = (unsigned int*)(ws + off); off += align_up((size_t)E * 4);
    int*          sorted_src = (int*)(ws + off);          off += align_up((size_t)E * 4);
    float*        xsA        = (float*)(ws + off);        off += align_up((size_t)totalK * 4);
    float*        xsB        = (float*)(ws + off);        off += align_up((size_t)totalK * 4);
    if (off > ws_size) return;

    float* out = (float*)d_out;

    const int BLK = 256;
    const int grid_e = 2048;                            // multiple of 8
    const int grid_v = 2048;
    const int nblkB = (NB + SCAN_BLK - 1) / SCAN_BLK;   // 10
    const int grid_nb = (NB + 255) / 256;
    const int grid_g = (n_nodes * KD + BLK - 1) / BLK;  // 1 wave/node

    // bucket partition + exact per-bucket sort
    hipMemsetAsync(cntb, 0, (size_t)NB * 4, stream);
    bhist_kernel<<<256, BLK, (size_t)NB * 4, stream>>>(dst, cntb, E, NB);
    scan1_kernel<<<nblkB, SCAN_BLK, 0, stream>>>(cntb, bptr, blk_sums, NB);
    scan2_kernel<<<1, 1024, 0, stream>>>(blk_sums, nblkB);
    scan3b_kernel<<<grid_nb, 256, 0, stream>>>(bptr, blk_sums, cursor, NB, E);
    part_kernel<<<grid_e, BLK, 0, stream>>>(src, dst, cursor, staged, E);
    bsort_kernel<<<NB, BLK, 0, stream>>>(staged, bptr, sorted_src, row_ptr, r,
                                         n_nodes, NB, E);

    // x0 combine + pre-scale
    combine_kernel<<<grid_v, BLK, 0, stream>>>((const float4*)Gu, (const float4*)Gi,
                                               (const float4*)Gut, (const float4*)Git,
                                               r, (float4*)out, (float4*)xsA, nu4, total4);

    // propagation
    float* xcur = xsA;
    float* xnxt = xsB;
    for (int k = 0; k < n_layers; ++k) {
        float alpha = 1.0f / (float)(k + 2);
        int last = (k == n_layers - 1) ? 1 : 0;
        gather_kernel<<<grid_g, BLK, 0, stream>>>(row_ptr, sorted_src, r,
                                                  (const float4*)xcur,
                                                  (float4*)out, (float4*)xnxt,
                                                  alpha, n_nodes, last);
        float* t = xcur; xcur = xnxt; xnxt = t;
    }
}

// Round 8
// 344.399 us; speedup vs baseline: 1.6402x; 1.6402x over previous
//
#include <hip/hip_runtime.h>

#define KD 64        // embedding dim
#define NPC 1024     // nodes per coarse bucket (bucket = dst >> 10)
#define TILE 4096    // edges per csplit tile

// ---------------- build: coarse histogram ----------------

// LDS-aggregated histogram of dst>>10 (NBC counters, dynamic LDS)
__global__ void bhist_kernel(const int* __restrict__ dst, int* __restrict__ cntb,
                             int E, int NBC) {
    extern __shared__ int lcnt[];
    for (int i = threadIdx.x; i < NBC; i += blockDim.x) lcnt[i] = 0;
    __syncthreads();
    for (int i = blockIdx.x * blockDim.x + threadIdx.x; i < E; i += gridDim.x * blockDim.x)
        atomicAdd(&lcnt[dst[i] >> 10], 1);
    __syncthreads();
    for (int i = threadIdx.x; i < NBC; i += blockDim.x) {
        int v = lcnt[i];
        if (v) atomicAdd(&cntb[i], v);
    }
}

// single-block exclusive scan of NBC (<=256) counters -> bptr, cursor
__global__ void scan_small_kernel(const int* __restrict__ cnt, int* __restrict__ bptr,
                                  int* __restrict__ cursor, int n, int E) {
    __shared__ int s[256];
    int t = threadIdx.x;
    int v = (t < n) ? cnt[t] : 0;
    s[t] = v;
    __syncthreads();
    for (int off = 1; off < 256; off <<= 1) {
        int add = (t >= off) ? s[t - off] : 0;
        __syncthreads();
        s[t] += add;
        __syncthreads();
    }
    int excl = s[t] - v;
    if (t < n) { bptr[t] = excl; cursor[t] = excl; }
    if (t == 0) bptr[n] = E;
}

// ---------------- build: tile multisplit (pass 1) ----------------

// Each block processes tiles of TILE edges: LDS histogram over NBC coarse
// buckets, LDS scan, LDS-ordered scatter, per-bucket global reservation, then
// RANK-ORDERED flush: thread i writes ordered[i] -> runs of consecutive
// addresses per (tile,bucket) -> near-full-line coalesced stores, block-private.
__global__ __launch_bounds__(256)
void csplit_kernel(const int* __restrict__ src, const int* __restrict__ dst,
                   int* __restrict__ cursor, unsigned int* __restrict__ staged,
                   int E, int NBC, int ntiles) {
    __shared__ unsigned int  ord[TILE];      // 16 KB ordered packed entries
    __shared__ unsigned short obkt[TILE];    // 8 KB bucket id per ordered slot
    __shared__ int hist[256];
    __shared__ int lofs[256];
    __shared__ int gbase[256];
    int tid = threadIdx.x;

    for (int tile = blockIdx.x; tile < ntiles; tile += gridDim.x) {
        int e0 = tile * TILE;
        int n = E - e0; if (n > TILE) n = TILE;

        if (tid < NBC) hist[tid] = 0;
        __syncthreads();
        // pass A: tile histogram
        for (int i = tid; i < n; i += 256)
            atomicAdd(&hist[dst[e0 + i] >> 10], 1);
        __syncthreads();
        // exclusive scan (Hillis-Steele over 256)
        int v = (tid < NBC) ? hist[tid] : 0;
        lofs[tid] = v;
        __syncthreads();
        for (int off = 1; off < 256; off <<= 1) {
            int add = (tid >= off) ? lofs[tid - off] : 0;
            __syncthreads();
            lofs[tid] += add;
            __syncthreads();
        }
        int excl = lofs[tid] - v;     // own slot only
        lofs[tid] = excl;
        // reserve global space; reset hist as local cursor
        if (tid < NBC) {
            gbase[tid] = atomicAdd(&cursor[tid], v);
            hist[tid] = 0;
        }
        __syncthreads();
        // pass B: scatter into LDS-ordered buffer
        for (int i = tid; i < n; i += 256) {
            int dd = dst[e0 + i];
            int ss = src[e0 + i];
            int b = dd >> 10;
            int p = lofs[b] + atomicAdd(&hist[b], 1);
            ord[p] = (unsigned int)ss | (((unsigned int)dd & 1023u) << 18);
            obkt[p] = (unsigned short)b;
        }
        __syncthreads();
        // pass C: rank-ordered coalesced flush
        for (int i = tid; i < n; i += 256) {
            int b = obkt[i];
            staged[gbase[b] + (i - lofs[b])] = ord[i];
        }
        __syncthreads();   // LDS reused next tile
    }
}

// ---------------- build: exact per-bucket sort (pass 2) ----------------

// One block per coarse bucket: 1024-bin LDS counting sort within the bucket's
// contiguous window of sorted_src (single-block-owned -> L2-local writes).
// Emits row_ptr and r for its 1024 nodes.
__global__ __launch_bounds__(256)
void csort_kernel(const unsigned int* __restrict__ staged, const int* __restrict__ bptr,
                  int* __restrict__ sorted_src, int* __restrict__ row_ptr,
                  float* __restrict__ r, int n_nodes, int E) {
    __shared__ int cnt[NPC];
    __shared__ int lofs[NPC];
    __shared__ int wsum[256];
    int b = blockIdx.x;
    int tid = threadIdx.x;
    int begin = bptr[b], end = bptr[b + 1];

    for (int i = tid; i < NPC; i += 256) cnt[i] = 0;
    __syncthreads();
    // pass 1: per-node counts
    for (int i = begin + tid; i < end; i += 256)
        atomicAdd(&cnt[(staged[i] >> 18) & 1023u], 1);
    __syncthreads();
    // exclusive scan of 1024 bins: 4/thread serial + 256-thread block scan
    int base = tid * 4;
    int c0 = cnt[base], c1 = cnt[base + 1], c2 = cnt[base + 2], c3 = cnt[base + 3];
    int tsum = c0 + c1 + c2 + c3;
    wsum[tid] = tsum;
    __syncthreads();
    for (int off = 1; off < 256; off <<= 1) {
        int add = (tid >= off) ? wsum[tid - off] : 0;
        __syncthreads();
        wsum[tid] += add;
        __syncthreads();
    }
    int texcl = wsum[tid] - tsum;
    lofs[base]     = texcl;
    lofs[base + 1] = texcl + c0;
    lofs[base + 2] = texcl + c0 + c1;
    lofs[base + 3] = texcl + c0 + c1 + c2;
    // emit row_ptr + r for this thread's 4 nodes
    int node0 = b * NPC + base;
    int cc[4] = {c0, c1, c2, c3};
    for (int j = 0; j < 4; ++j) {
        int node = node0 + j;
        if (node < n_nodes) {
            row_ptr[node] = begin + lofs[base + j];
            r[node] = rsqrtf(fmaxf((float)cc[j], 1.0f));
        }
    }
    // reset cnt as cursor
    cnt[base] = 0; cnt[base + 1] = 0; cnt[base + 2] = 0; cnt[base + 3] = 0;
    if (b == 0 && tid == 0) row_ptr[n_nodes] = E;
    __syncthreads();
    // pass 2: scatter within the bucket window
    for (int i = begin + tid; i < end; i += 256) {
        unsigned int u = staged[i];
        int ld = (u >> 18) & 1023u;
        int p = begin + lofs[ld] + atomicAdd(&cnt[ld], 1);
        sorted_src[p] = (int)(u & 0x3FFFFu);
    }
}

// ---------------- embedding kernels ----------------

// x0 = (Gu+Gut | Gi+Git); out = x0; xs = x0 * r[node]  (all f32)
__global__ void combine_kernel(const float4* __restrict__ Gu, const float4* __restrict__ Gi,
                               const float4* __restrict__ Gut, const float4* __restrict__ Git,
                               const float* __restrict__ r,
                               float4* __restrict__ out, float4* __restrict__ xs,
                               int nu4, int total4) {
    for (int i = blockIdx.x * blockDim.x + threadIdx.x; i < total4; i += gridDim.x * blockDim.x) {
        float4 a, b;
        if (i < nu4) { a = Gu[i]; b = Gut[i]; }
        else         { a = Gi[i - nu4]; b = Git[i - nu4]; }
        float4 c;
        c.x = a.x + b.x; c.y = a.y + b.y; c.z = a.z + b.z; c.w = a.w + b.w;
        out[i] = c;
        float rr = r[i >> 4];   // 16 float4 per node row
        float4 sc;
        sc.x = c.x * rr; sc.y = c.y * rr; sc.z = c.z * rr; sc.w = c.w * rr;
        xs[i] = sc;
    }
}

// one wave per dst node; 4 subgroups x 16 lanes; each subgroup processes 4 edges
// per iteration with 4 INDEPENDENT float4 loads issued before accumulation.
// y = acc * r; out += alpha*y; xs_next = y * r (skip on last layer).
__global__ __launch_bounds__(256)
void gather_kernel(const int* __restrict__ row_ptr, const int* __restrict__ sorted_src,
                   const float* __restrict__ r, const float4* __restrict__ xs,
                   float4* __restrict__ out, float4* __restrict__ xs_next,
                   float alpha, int N, int last) {
    int wid = (blockIdx.x * blockDim.x + threadIdx.x) >> 6;
    int lane = threadIdx.x & 63;
    if (wid >= N) return;
    int start = row_ptr[wid];
    int end   = row_ptr[wid + 1];
    int sub = lane >> 4;      // edge subgroup 0..3
    int li  = lane & 15;      // float4 slot within the 64-dim row

    float ax = 0.f, ay = 0.f, az = 0.f, aw = 0.f;
    for (int base = start; base < end; base += 64) {
        int nb = end - base; if (nb > 64) nb = 64;
        int eaddr = base + lane;
        int laste = end - 1;
        if (eaddr > laste) eaddr = laste;
        int es = sorted_src[eaddr];              // 64 edge ids (clamped tail)
        for (int c = 0; c < nb; c += 16) {
            int j0 = c + sub * 4;
            int s0 = __shfl(es, j0 + 0);
            int s1 = __shfl(es, j0 + 1);
            int s2 = __shfl(es, j0 + 2);
            int s3 = __shfl(es, j0 + 3);
            if (j0 < nb) {
                float m0 = 1.f;
                float m1 = (j0 + 1 < nb) ? 1.f : 0.f;
                float m2 = (j0 + 2 < nb) ? 1.f : 0.f;
                float m3 = (j0 + 3 < nb) ? 1.f : 0.f;
                float4 v0 = xs[s0 * 16 + li];
                float4 v1 = xs[s1 * 16 + li];
                float4 v2 = xs[s2 * 16 + li];
                float4 v3 = xs[s3 * 16 + li];
                ax += m0 * v0.x + m1 * v1.x + m2 * v2.x + m3 * v3.x;
                ay += m0 * v0.y + m1 * v1.y + m2 * v2.y + m3 * v3.y;
                az += m0 * v0.z + m1 * v1.z + m2 * v2.z + m3 * v3.z;
                aw += m0 * v0.w + m1 * v1.w + m2 * v2.w + m3 * v3.w;
            }
        }
    }
    ax += __shfl_xor(ax, 16); ay += __shfl_xor(ay, 16);
    az += __shfl_xor(az, 16); aw += __shfl_xor(aw, 16);
    ax += __shfl_xor(ax, 32); ay += __shfl_xor(ay, 32);
    az += __shfl_xor(az, 32); aw += __shfl_xor(aw, 32);

    if (lane < 16) {
        float rr = r[wid];
        float yx = ax * rr, yy = ay * rr, yz = az * rr, yw = aw * rr;
        int idx = wid * 16 + lane;
        float4 o = out[idx];
        o.x += alpha * yx; o.y += alpha * yy; o.z += alpha * yz; o.w += alpha * yw;
        out[idx] = o;
        if (!last) {
            float4 p;
            p.x = yx * rr; p.y = yy * rr; p.z = yz * rr; p.w = yw * rr;
            xs_next[idx] = p;
        }
    }
}

// ---------------- launch ----------------

extern "C" void kernel_launch(void* const* d_in, const int* in_sizes, int n_in,
                              void* d_out, int out_size, void* d_ws, size_t ws_size,
                              hipStream_t stream) {
    const float* Gu  = (const float*)d_in[0];
    const float* Gi  = (const float*)d_in[1];
    const float* Gut = (const float*)d_in[2];
    const float* Git = (const float*)d_in[3];
    const int*   edge_index = (const int*)d_in[4];
    const int n_layers = 3;

    const int nuK = in_sizes[0];
    const int niK = in_sizes[1];
    const int n_nodes = (nuK + niK) / KD;        // 150000
    const int E = in_sizes[4] / 2;               // 2,000,000
    const int totalK = nuK + niK;
    const int total4 = totalK / 4;
    const int nu4 = nuK / 4;
    const int NBC = (n_nodes + NPC - 1) / NPC;   // 147 coarse buckets
    const int ntiles = (E + TILE - 1) / TILE;    // 489

    const int* src = edge_index;
    const int* dst = edge_index + E;

    auto align_up = [](size_t v) { return (v + 255) & ~(size_t)255; };
    char* ws = (char*)d_ws;
    size_t off = 0;
    int*          cntb       = (int*)(ws + off);          off += align_up((size_t)NBC * 4);
    int*          bptr       = (int*)(ws + off);          off += align_up((size_t)(NBC + 1) * 4);
    int*          cursor     = (int*)(ws + off);          off += align_up((size_t)NBC * 4);
    int*          row_ptr    = (int*)(ws + off);          off += align_up((size_t)(n_nodes + 1) * 4);
    float*        r          = (float*)(ws + off);        off += align_up((size_t)n_nodes * 4);
    unsigned int* staged     = (unsigned int*)(ws + off); off += align_up((size_t)E * 4);
    int*          sorted_src = (int*)(ws + off);          off += align_up((size_t)E * 4);
    float*        xsA        = (float*)(ws + off);        off += align_up((size_t)totalK * 4);
    float*        xsB        = (float*)(ws + off);        off += align_up((size_t)totalK * 4);
    if (off > ws_size) return;

    float* out = (float*)d_out;

    const int BLK = 256;
    const int grid_v = 2048;
    const int grid_g = (n_nodes * KD + BLK - 1) / BLK;  // 1 wave/node

    // build: coarse hist -> scan -> tile multisplit -> per-bucket exact sort
    hipMemsetAsync(cntb, 0, (size_t)NBC * 4, stream);
    bhist_kernel<<<256, BLK, (size_t)NBC * 4, stream>>>(dst, cntb, E, NBC);
    scan_small_kernel<<<1, 256, 0, stream>>>(cntb, bptr, cursor, NBC, E);
    csplit_kernel<<<ntiles, BLK, 0, stream>>>(src, dst, cursor, staged, E, NBC, ntiles);
    csort_kernel<<<NBC, BLK, 0, stream>>>(staged, bptr, sorted_src, row_ptr, r,
                                          n_nodes, E);

    // x0 combine + pre-scale
    combine_kernel<<<grid_v, BLK, 0, stream>>>((const float4*)Gu, (const float4*)Gi,
                                               (const float4*)Gut, (const float4*)Git,
                                               r, (float4*)out, (float4*)xsA, nu4, total4);

    // propagation
    float* xcur = xsA;
    float* xnxt = xsB;
    for (int k = 0; k < n_layers; ++k) {
        float alpha = 1.0f / (float)(k + 2);
        int last = (k == n_layers - 1) ? 1 : 0;
        gather_kernel<<<grid_g, BLK, 0, stream>>>(row_ptr, sorted_src, r,
                                                  (const float4*)xcur,
                                                  (float4*)out, (float4*)xnxt,
                                                  alpha, n_nodes, last);
        float* t = xcur; xcur = xnxt; xnxt = t;
    }
}

// Round 9
// 275.837 us; speedup vs baseline: 2.0479x; 1.2486x over previous
//
#include <hip/hip_runtime.h>
#include <hip/hip_fp16.h>

#define KD 64        // embedding dim
#define NPC 1024     // nodes per coarse bucket (bucket = dst >> 10)
#define TILE 4096    // edges per csplit tile

__device__ __forceinline__ float h2f(unsigned short u) {
    return __half2float(__ushort_as_half(u));
}
__device__ __forceinline__ unsigned short f2h(float f) {
    return __half_as_ushort(__float2half(f));
}

// ---------------- build: coarse histogram ----------------

__global__ void bhist_kernel(const int* __restrict__ dst, int* __restrict__ cntb,
                             int E, int NBC) {
    extern __shared__ int lcnt[];
    for (int i = threadIdx.x; i < NBC; i += blockDim.x) lcnt[i] = 0;
    __syncthreads();
    for (int i = blockIdx.x * blockDim.x + threadIdx.x; i < E; i += gridDim.x * blockDim.x)
        atomicAdd(&lcnt[dst[i] >> 10], 1);
    __syncthreads();
    for (int i = threadIdx.x; i < NBC; i += blockDim.x) {
        int v = lcnt[i];
        if (v) atomicAdd(&cntb[i], v);
    }
}

// single-block exclusive scan of NBC (<=256) counters -> bptr, cursor
__global__ void scan_small_kernel(const int* __restrict__ cnt, int* __restrict__ bptr,
                                  int* __restrict__ cursor, int n, int E) {
    __shared__ int s[256];
    int t = threadIdx.x;
    int v = (t < n) ? cnt[t] : 0;
    s[t] = v;
    __syncthreads();
    for (int off = 1; off < 256; off <<= 1) {
        int add = (t >= off) ? s[t - off] : 0;
        __syncthreads();
        s[t] += add;
        __syncthreads();
    }
    int excl = s[t] - v;
    if (t < n) { bptr[t] = excl; cursor[t] = excl; }
    if (t == 0) bptr[n] = E;
}

// ---------------- build: tile multisplit (pass 1) ----------------

__global__ __launch_bounds__(256)
void csplit_kernel(const int* __restrict__ src, const int* __restrict__ dst,
                   int* __restrict__ cursor, unsigned int* __restrict__ staged,
                   int E, int NBC, int ntiles) {
    __shared__ unsigned int  ord[TILE];      // 16 KB ordered packed entries
    __shared__ unsigned short obkt[TILE];    // 8 KB bucket id per ordered slot
    __shared__ int hist[256];
    __shared__ int lofs[256];
    __shared__ int gbase[256];
    int tid = threadIdx.x;

    for (int tile = blockIdx.x; tile < ntiles; tile += gridDim.x) {
        int e0 = tile * TILE;
        int n = E - e0; if (n > TILE) n = TILE;

        if (tid < NBC) hist[tid] = 0;
        __syncthreads();
        for (int i = tid; i < n; i += 256)
            atomicAdd(&hist[dst[e0 + i] >> 10], 1);
        __syncthreads();
        int v = (tid < NBC) ? hist[tid] : 0;
        lofs[tid] = v;
        __syncthreads();
        for (int off = 1; off < 256; off <<= 1) {
            int add = (tid >= off) ? lofs[tid - off] : 0;
            __syncthreads();
            lofs[tid] += add;
            __syncthreads();
        }
        int excl = lofs[tid] - v;
        lofs[tid] = excl;
        if (tid < NBC) {
            gbase[tid] = atomicAdd(&cursor[tid], v);
            hist[tid] = 0;
        }
        __syncthreads();
        for (int i = tid; i < n; i += 256) {
            int dd = dst[e0 + i];
            int ss = src[e0 + i];
            int b = dd >> 10;
            int p = lofs[b] + atomicAdd(&hist[b], 1);
            ord[p] = (unsigned int)ss | (((unsigned int)dd & 1023u) << 18);
            obkt[p] = (unsigned short)b;
        }
        __syncthreads();
        for (int i = tid; i < n; i += 256) {
            int b = obkt[i];
            staged[gbase[b] + (i - lofs[b])] = ord[i];
        }
        __syncthreads();
    }
}

// ---------------- build: exact per-bucket sort (pass 2) ----------------

__global__ __launch_bounds__(256)
void csort_kernel(const unsigned int* __restrict__ staged, const int* __restrict__ bptr,
                  int* __restrict__ sorted_src, int* __restrict__ row_ptr,
                  float* __restrict__ r, float* __restrict__ rinv,
                  int n_nodes, int E) {
    __shared__ int cnt[NPC];
    __shared__ int lofs[NPC];
    __shared__ int wsum[256];
    int b = blockIdx.x;
    int tid = threadIdx.x;
    int begin = bptr[b], end = bptr[b + 1];

    for (int i = tid; i < NPC; i += 256) cnt[i] = 0;
    __syncthreads();
    for (int i = begin + tid; i < end; i += 256)
        atomicAdd(&cnt[(staged[i] >> 18) & 1023u], 1);
    __syncthreads();
    int base = tid * 4;
    int c0 = cnt[base], c1 = cnt[base + 1], c2 = cnt[base + 2], c3 = cnt[base + 3];
    int tsum = c0 + c1 + c2 + c3;
    wsum[tid] = tsum;
    __syncthreads();
    for (int off = 1; off < 256; off <<= 1) {
        int add = (tid >= off) ? wsum[tid - off] : 0;
        __syncthreads();
        wsum[tid] += add;
        __syncthreads();
    }
    int texcl = wsum[tid] - tsum;
    lofs[base]     = texcl;
    lofs[base + 1] = texcl + c0;
    lofs[base + 2] = texcl + c0 + c1;
    lofs[base + 3] = texcl + c0 + c1 + c2;
    int node0 = b * NPC + base;
    int cc[4] = {c0, c1, c2, c3};
    for (int j = 0; j < 4; ++j) {
        int node = node0 + j;
        if (node < n_nodes) {
            float d = fmaxf((float)cc[j], 1.0f);
            row_ptr[node] = begin + lofs[base + j];
            r[node] = rsqrtf(d);
            rinv[node] = sqrtf(d);
        }
    }
    cnt[base] = 0; cnt[base + 1] = 0; cnt[base + 2] = 0; cnt[base + 3] = 0;
    if (b == 0 && tid == 0) row_ptr[n_nodes] = E;
    __syncthreads();
    for (int i = begin + tid; i < end; i += 256) {
        unsigned int u = staged[i];
        int ld = (u >> 18) & 1023u;
        int p = begin + lofs[ld] + atomicAdd(&cnt[ld], 1);
        sorted_src[p] = (int)(u & 0x3FFFFu);
    }
}

// ---------------- embedding kernels ----------------

// xs0 = fp16((Gu+Gut | Gi+Git) * r[node])
__global__ void combine_kernel(const float4* __restrict__ Gu, const float4* __restrict__ Gi,
                               const float4* __restrict__ Gut, const float4* __restrict__ Git,
                               const float* __restrict__ r,
                               ushort4* __restrict__ xs,
                               int nu4, int total4) {
    for (int i = blockIdx.x * blockDim.x + threadIdx.x; i < total4; i += gridDim.x * blockDim.x) {
        float4 a, b;
        if (i < nu4) { a = Gu[i]; b = Gut[i]; }
        else         { a = Gi[i - nu4]; b = Git[i - nu4]; }
        float rr = r[i >> 4];   // 16 ushort4 per node row
        ushort4 p;
        p.x = f2h((a.x + b.x) * rr); p.y = f2h((a.y + b.y) * rr);
        p.z = f2h((a.z + b.z) * rr); p.w = f2h((a.w + b.w) * rr);
        xs[i] = p;
    }
}

// one wave per dst node; 4 subgroups x 16 lanes; 4 edges per subgroup per iter
// with 4 INDEPENDENT ushort4 (fp16) loads. xs_next = fp16(acc * r * r).
__global__ __launch_bounds__(256)
void gather_kernel(const int* __restrict__ row_ptr, const int* __restrict__ sorted_src,
                   const float* __restrict__ r, const ushort4* __restrict__ xs,
                   ushort4* __restrict__ xs_next, int N) {
    int wid = (blockIdx.x * blockDim.x + threadIdx.x) >> 6;
    int lane = threadIdx.x & 63;
    if (wid >= N) return;
    int start = row_ptr[wid];
    int end   = row_ptr[wid + 1];
    int sub = lane >> 4;      // edge subgroup 0..3
    int li  = lane & 15;      // ushort4 slot within the 64-dim row

    float ax = 0.f, ay = 0.f, az = 0.f, aw = 0.f;
    for (int base = start; base < end; base += 64) {
        int nb = end - base; if (nb > 64) nb = 64;
        int eaddr = base + lane;
        int laste = end - 1;
        if (eaddr > laste) eaddr = laste;
        int es = sorted_src[eaddr];              // 64 edge ids (clamped tail)
        for (int c = 0; c < nb; c += 16) {
            int j0 = c + sub * 4;
            int s0 = __shfl(es, j0 + 0);
            int s1 = __shfl(es, j0 + 1);
            int s2 = __shfl(es, j0 + 2);
            int s3 = __shfl(es, j0 + 3);
            if (j0 < nb) {
                float m1 = (j0 + 1 < nb) ? 1.f : 0.f;
                float m2 = (j0 + 2 < nb) ? 1.f : 0.f;
                float m3 = (j0 + 3 < nb) ? 1.f : 0.f;
                ushort4 u0 = xs[s0 * 16 + li];
                ushort4 u1 = xs[s1 * 16 + li];
                ushort4 u2 = xs[s2 * 16 + li];
                ushort4 u3 = xs[s3 * 16 + li];
                ax += h2f(u0.x) + m1 * h2f(u1.x) + m2 * h2f(u2.x) + m3 * h2f(u3.x);
                ay += h2f(u0.y) + m1 * h2f(u1.y) + m2 * h2f(u2.y) + m3 * h2f(u3.y);
                az += h2f(u0.z) + m1 * h2f(u1.z) + m2 * h2f(u2.z) + m3 * h2f(u3.z);
                aw += h2f(u0.w) + m1 * h2f(u1.w) + m2 * h2f(u2.w) + m3 * h2f(u3.w);
            }
        }
    }
    ax += __shfl_xor(ax, 16); ay += __shfl_xor(ay, 16);
    az += __shfl_xor(az, 16); aw += __shfl_xor(aw, 16);
    ax += __shfl_xor(ax, 32); ay += __shfl_xor(ay, 32);
    az += __shfl_xor(az, 32); aw += __shfl_xor(aw, 32);

    if (lane < 16) {
        float rr = r[wid];
        float s = rr * rr;
        ushort4 p;
        p.x = f2h(ax * s); p.y = f2h(ay * s);
        p.z = f2h(az * s); p.w = f2h(aw * s);
        xs_next[wid * 16 + lane] = p;
    }
}

// out = (Gu+Gut | Gi+Git) + rinv[node] * (a1*xs1 + a2*xs2 + a3*xs3)
__global__ void epilogue_kernel(const float4* __restrict__ Gu, const float4* __restrict__ Gi,
                                const float4* __restrict__ Gut, const float4* __restrict__ Git,
                                const float* __restrict__ rinv,
                                const ushort4* __restrict__ xs1,
                                const ushort4* __restrict__ xs2,
                                const ushort4* __restrict__ xs3,
                                float4* __restrict__ out,
                                int nu4, int total4) {
    const float a1 = 0.5f, a2 = 1.0f / 3.0f, a3 = 0.25f;
    for (int i = blockIdx.x * blockDim.x + threadIdx.x; i < total4; i += gridDim.x * blockDim.x) {
        float4 a, b;
        if (i < nu4) { a = Gu[i]; b = Gut[i]; }
        else         { a = Gi[i - nu4]; b = Git[i - nu4]; }
        float rv = rinv[i >> 4];
        ushort4 u1 = xs1[i];
        ushort4 u2 = xs2[i];
        ushort4 u3 = xs3[i];
        float4 o;
        o.x = a.x + b.x + rv * (a1 * h2f(u1.x) + a2 * h2f(u2.x) + a3 * h2f(u3.x));
        o.y = a.y + b.y + rv * (a1 * h2f(u1.y) + a2 * h2f(u2.y) + a3 * h2f(u3.y));
        o.z = a.z + b.z + rv * (a1 * h2f(u1.z) + a2 * h2f(u2.z) + a3 * h2f(u3.z));
        o.w = a.w + b.w + rv * (a1 * h2f(u1.w) + a2 * h2f(u2.w) + a3 * h2f(u3.w));
        out[i] = o;
    }
}

// ---------------- launch ----------------

extern "C" void kernel_launch(void* const* d_in, const int* in_sizes, int n_in,
                              void* d_out, int out_size, void* d_ws, size_t ws_size,
                              hipStream_t stream) {
    const float* Gu  = (const float*)d_in[0];
    const float* Gi  = (const float*)d_in[1];
    const float* Gut = (const float*)d_in[2];
    const float* Git = (const float*)d_in[3];
    const int*   edge_index = (const int*)d_in[4];

    const int nuK = in_sizes[0];
    const int niK = in_sizes[1];
    const int n_nodes = (nuK + niK) / KD;        // 150000
    const int E = in_sizes[4] / 2;               // 2,000,000
    const int totalK = nuK + niK;
    const int total4 = totalK / 4;
    const int nu4 = nuK / 4;
    const int NBC = (n_nodes + NPC - 1) / NPC;   // 147 coarse buckets
    const int ntiles = (E + TILE - 1) / TILE;    // 489

    const int* src = edge_index;
    const int* dst = edge_index + E;

    auto align_up = [](size_t v) { return (v + 255) & ~(size_t)255; };
    char* ws = (char*)d_ws;
    size_t off = 0;
    int*          cntb       = (int*)(ws + off);          off += align_up((size_t)NBC * 4);
    int*          bptr       = (int*)(ws + off);          off += align_up((size_t)(NBC + 1) * 4);
    int*          cursor     = (int*)(ws + off);          off += align_up((size_t)NBC * 4);
    int*          row_ptr    = (int*)(ws + off);          off += align_up((size_t)(n_nodes + 1) * 4);
    float*        r          = (float*)(ws + off);        off += align_up((size_t)n_nodes * 4);
    float*        rinv       = (float*)(ws + off);        off += align_up((size_t)n_nodes * 4);
    unsigned int* staged     = (unsigned int*)(ws + off); off += align_up((size_t)E * 4);
    int*          sorted_src = (int*)(ws + off);          off += align_up((size_t)E * 4);
    unsigned short* xs0      = (unsigned short*)(ws + off); off += align_up((size_t)totalK * 2);
    unsigned short* xs1      = (unsigned short*)(ws + off); off += align_up((size_t)totalK * 2);
    unsigned short* xs2      = (unsigned short*)(ws + off); off += align_up((size_t)totalK * 2);
    unsigned short* xs3      = (unsigned short*)(ws + off); off += align_up((size_t)totalK * 2);
    if (off > ws_size) return;

    float* out = (float*)d_out;

    const int BLK = 256;
    const int grid_v = 2048;
    const int grid_g = (n_nodes * KD + BLK - 1) / BLK;  // 1 wave/node

    // build: coarse hist -> scan -> tile multisplit -> per-bucket exact sort
    hipMemsetAsync(cntb, 0, (size_t)NBC * 4, stream);
    bhist_kernel<<<256, BLK, (size_t)NBC * 4, stream>>>(dst, cntb, E, NBC);
    scan_small_kernel<<<1, 256, 0, stream>>>(cntb, bptr, cursor, NBC, E);
    csplit_kernel<<<ntiles, BLK, 0, stream>>>(src, dst, cursor, staged, E, NBC, ntiles);
    csort_kernel<<<NBC, BLK, 0, stream>>>(staged, bptr, sorted_src, row_ptr, r, rinv,
                                          n_nodes, E);

    // xs0 = fp16(x0 * r)
    combine_kernel<<<grid_v, BLK, 0, stream>>>((const float4*)Gu, (const float4*)Gi,
                                               (const float4*)Gut, (const float4*)Git,
                                               r, (ushort4*)xs0, nu4, total4);

    // propagation (each layer writes xs_k = fp16(y_k * r))
    gather_kernel<<<grid_g, BLK, 0, stream>>>(row_ptr, sorted_src, r,
                                              (const ushort4*)xs0, (ushort4*)xs1, n_nodes);
    gather_kernel<<<grid_g, BLK, 0, stream>>>(row_ptr, sorted_src, r,
                                              (const ushort4*)xs1, (ushort4*)xs2, n_nodes);
    gather_kernel<<<grid_g, BLK, 0, stream>>>(row_ptr, sorted_src, r,
                                              (const ushort4*)xs2, (ushort4*)xs3, n_nodes);

    // out = x0 + rinv * (a1*xs1 + a2*xs2 + a3*xs3)
    epilogue_kernel<<<grid_v, BLK, 0, stream>>>((const float4*)Gu, (const float4*)Gi,
                                                (const float4*)Gut, (const float4*)Git,
                                                rinv, (const ushort4*)xs1,
                                                (const ushort4*)xs2, (const ushort4*)xs3,
                                                (float4*)out, nu4, total4);
}